// Round 7
// baseline (277.648 us; speedup 1.0000x reference)
//
#include <hip/hip_runtime.h>

// hardwiredAttention: out[b,i,h] = sum_j w[b,i,j] * h_t[j,b,h]
//   w = m_i*m_j*relu(domain[cog,r]-d) / max(w)
// R7: abandon global_load_lds for the HBM stream (evidence R3-R6: delivery
// pinned ~5 B/cyc/CU, depth/phase/policy-insensitive => per-CU LDS-DMA queue
// ~4KB is the cap). Stage via VGPR global loads + ds_write_b128; loads stay
// in flight across lgkm-only asm barriers. 1 block/CU, 128-row tiles, all 8
// waves stage+compute. T staged to LDS per step (no VGPR T buffer).

#define B_   64
#define N_   512
#define H_   128
#define NCOG 72
#define NRB  72

typedef __bf16 bf16x8 __attribute__((ext_vector_type(8)));
typedef float  f32x4  __attribute__((ext_vector_type(4)));

// ---------- h_t[j][b][h] fp32 -> T[b][h][j] bf16 ----------
__global__ __launch_bounds__(256) void k_transpose(const float* __restrict__ ht,
                                                   __bf16* __restrict__ T) {
    __shared__ __bf16 tile[32][136];
    const int jt = blockIdx.x * 32;
    const int b  = blockIdx.y;
    const int t  = threadIdx.x;
    {
        const int jj = t >> 3;
        const int h0 = (t & 7) << 4;
        const float* src = ht + ((size_t)(jt + jj) * B_ + b) * H_ + h0;
        float4 v0 = *(const float4*)(src + 0);
        float4 v1 = *(const float4*)(src + 4);
        float4 v2 = *(const float4*)(src + 8);
        float4 v3 = *(const float4*)(src + 12);
        __bf16* dst = &tile[jj][h0];
        dst[0]=(__bf16)v0.x; dst[1]=(__bf16)v0.y; dst[2]=(__bf16)v0.z; dst[3]=(__bf16)v0.w;
        dst[4]=(__bf16)v1.x; dst[5]=(__bf16)v1.y; dst[6]=(__bf16)v1.z; dst[7]=(__bf16)v1.w;
        dst[8]=(__bf16)v2.x; dst[9]=(__bf16)v2.y; dst[10]=(__bf16)v2.z; dst[11]=(__bf16)v2.w;
        dst[12]=(__bf16)v3.x; dst[13]=(__bf16)v3.y; dst[14]=(__bf16)v3.z; dst[15]=(__bf16)v3.w;
    }
    __syncthreads();
    {
        const int h  = t >> 1;
        const int j0 = (t & 1) << 4;
        union { bf16x8 v[2]; __bf16 e[16]; } ob;
        #pragma unroll
        for (int q = 0; q < 16; ++q) ob.e[q] = tile[j0 + q][h];
        __bf16* dst = T + ((size_t)b * H_ + h) * N_ + jt + j0;
        *(bf16x8*)(dst + 0) = ob.v[0];
        *(bf16x8*)(dst + 8) = ob.v[1];
    }
}

// ---------- fused kernel: VGPR-staged pipeline, lgkm-only barriers ----------
__global__ __launch_bounds__(512, 1) void k_main(const int* __restrict__ cog,
                                                 const int* __restrict__ rmat,
                                                 const float* __restrict__ dmat,
                                                 const float* __restrict__ mask,
                                                 const float* __restrict__ domain,
                                                 const __bf16* __restrict__ T,
                                                 float* __restrict__ out,
                                                 unsigned int* __restrict__ gmax) {
    __shared__ int    wt[2][3][4096];   // 96 KB: [buf][arr][row*32 + xor-swz chunk]
    __shared__ __bf16 tt[2][H_][32];    // 16 KB: [buf][h][k]
    __shared__ float  sdom[NCOG * NRB]; // 20736 B
    __shared__ float  smask[N_];        // 2048 B
    __shared__ float  swmax[8];

    const int id = blockIdx.x;                    // 256 blocks = 1 round
    const int b  = (id & 7) + 8 * (id >> 5);      // same-b blocks share an XCD
    const int i0 = ((id >> 3) & 3) * 128;

    const int t = threadIdx.x, wave = t >> 6, lane = t & 63;

    for (int k = t; k < NCOG * NRB; k += 512) sdom[k] = domain[k];
    for (int k = t; k < N_; k += 512) smask[k] = mask[b * N_ + k];

    const size_t robase = ((size_t)b * N_ + i0) * N_;

    // ---- staging descriptors: 7 chunks/wave (6 W-arrays + 1 T) ----
    const int l8 = lane >> 3, l7 = lane & 7;
    const int* gw[6];   // global src (per step: + s*32)
    int        wo[6];   // LDS int offset inside wt[buf]
    #pragma unroll
    for (int q = 0; q < 6; ++q) {
        const int m = wave + 8 * q, a = m >> 4, sub = m & 15;
        const int row = sub * 8 + l8;             // local row 0..127
        const int* base = (a == 0) ? cog : (a == 1) ? rmat : (const int*)dmat;
        gw[q] = base + robase + (size_t)row * N_ + l7 * 4;
        wo[q] = a * 4096 + row * 32 + ((l7 ^ l8) * 4);   // chunk c stored at c^(row&7)
    }
    const __bf16* gT = T + (size_t)b * H_ * N_
                         + (size_t)(wave * 16 + (lane >> 2)) * N_ + (lane & 3) * 8;
    __bf16* ttw0 = &tt[0][wave * 16 + (lane >> 2)][(lane & 3) * 8];
    __bf16* ttw1 = &tt[1][wave * 16 + (lane >> 2)][(lane & 3) * 8];

    int4 ldw[2][6]; int4 ldt[2];

    #define ISSUE(n, par) do {                                                  \
        const int kk_ = (n) * 32;                                               \
        _Pragma("unroll")                                                       \
        for (int q = 0; q < 6; ++q) ldw[par][q] = *(const int4*)(gw[q] + kk_);  \
        ldt[par] = *(const int4*)(gT + kk_); } while (0)

    #define STAGE(par) do {                                                     \
        int* wb = &wt[par][0][0];                                               \
        _Pragma("unroll")                                                       \
        for (int q = 0; q < 6; ++q) *(int4*)(wb + wo[q]) = ldw[par][q];         \
        *(int4*)((par) ? ttw1 : ttw0) = ldt[par]; } while (0)

    // ---- consumer descriptors ----
    const int quad = lane >> 4, lrow = lane & 15;
    const int row  = wave * 16 + lrow;            // local 0..127
    const int g0   = row * 32 + (((quad * 2) ^ (lrow & 7)) * 4);
    const int g1   = g0 ^ 4;                      // chunk 2q and 2q+1 positions

    f32x4 acc[8];
    #pragma unroll
    for (int i = 0; i < 8; ++i) acc[i] = (f32x4)0.0f;
    float wmax = 0.0f;

    #define COMPUTE(s, par) do {                                                \
        const int jb = (s) * 32 + quad * 8;                                     \
        const int* wp = &wt[par][0][0];                                         \
        union { int4 v[2]; int   e[8]; } ci, ri;                                \
        union { int4 v[2]; float e[8]; } di;                                    \
        ci.v[0] = *(const int4*)(wp + g0);        ci.v[1] = *(const int4*)(wp + g1);        \
        ri.v[0] = *(const int4*)(wp + 4096 + g0); ri.v[1] = *(const int4*)(wp + 4096 + g1); \
        di.v[0] = *(const int4*)(wp + 8192 + g0); di.v[1] = *(const int4*)(wp + 8192 + g1); \
        bf16x8 bf[8];                                                           \
        _Pragma("unroll")                                                       \
        for (int nt = 0; nt < 8; ++nt)                                          \
            bf[nt] = *(const bf16x8*)&tt[par][nt * 16 + lrow][quad * 8];        \
        union { bf16x8 v8; __bf16 e[8]; } af;                                   \
        _Pragma("unroll")                                                       \
        for (int q = 0; q < 8; ++q) {                                           \
            float val = sdom[ci.e[q] * NRB + ri.e[q]] - di.e[q];                \
            val = fmaxf(val, 0.0f) * smask[jb + q];                             \
            wmax = fmaxf(wmax, val);                                            \
            af.e[q] = (__bf16)val;                                              \
        }                                                                       \
        _Pragma("unroll")                                                       \
        for (int nt = 0; nt < 8; ++nt)                                          \
            acc[nt] = __builtin_amdgcn_mfma_f32_16x16x32_bf16(af.v8, bf[nt], acc[nt], 0, 0, 0); \
    } while (0)

    // lgkm-only barrier: LDS writes published, global loads stay in flight
    #define LBAR asm volatile("s_waitcnt lgkmcnt(0)\n\ts_barrier" ::: "memory")

    // prologue: batches 0,1 in flight; stage batch 0 (compiler waits vmcnt(7))
    ISSUE(0, 0);
    ISSUE(1, 1);
    STAGE(0);
    LBAR;

    // manual 2-step unroll so all parity indices are compile-time constants
    for (int sp = 0; sp < 8; ++sp) {
        const int s0 = sp * 2, s1 = s0 + 1;
        if (s0 < 14) ISSUE(s0 + 2, 0);    // batch s0+2 (even -> ldw[0])
        STAGE(1);                          // batch s0+1 (odd), loaded 1 step ago
        COMPUTE(s0, 0);
        LBAR;
        if (s1 < 14) ISSUE(s1 + 2, 1);    // batch s1+2 (odd)
        if (s1 < 15) STAGE(0);            // batch s1+1 (even)
        COMPUTE(s1, 1);
        LBAR;
    }
    #undef ISSUE
    #undef STAGE
    #undef COMPUTE
    #undef LBAR

    wmax *= smask[i0 + row];   // fold mask_i (all of this lane's w are row `row`)

    // block max -> one atomic
    #pragma unroll
    for (int off = 32; off > 0; off >>= 1)
        wmax = fmaxf(wmax, __shfl_down(wmax, off));
    if (lane == 0) swmax[wave] = wmax;
    __syncthreads();
    if (t == 0) {
        float m = swmax[0];
        #pragma unroll
        for (int w = 1; w < 8; ++w) m = fmaxf(m, swmax[w]);
        atomicMax(gmax, __float_as_uint(m));   // floats >= 0: uint cmp == float cmp
    }

    // unnormalized output; D layout: col=lane&15, row=quad*4+reg
    const int orow0 = i0 + wave * 16 + quad * 4;
    #pragma unroll
    for (int nt = 0; nt < 8; ++nt) {
        #pragma unroll
        for (int r = 0; r < 4; ++r)
            out[((size_t)b * N_ + orow0 + r) * H_ + nt * 16 + lrow] = acc[nt][r];
    }
}

// ---------- scale by m_i / gmax ----------
__global__ __launch_bounds__(256) void k_scale(float* __restrict__ out,
                                               const float* __restrict__ mask,
                                               const unsigned int* __restrict__ gmax) {
    const float inv = 1.0f / __uint_as_float(*gmax);
    const int idx = blockIdx.x * 256 + threadIdx.x;     // 1,048,576 float4s
    const float m = mask[idx >> 5] * inv;               // 32 float4 per (b,i) row
    float4* p = (float4*)out;
    float4 v = p[idx];
    v.x *= m; v.y *= m; v.z *= m; v.w *= m;
    p[idx] = v;
}

extern "C" void kernel_launch(void* const* d_in, const int* in_sizes, int n_in,
                              void* d_out, int out_size, void* d_ws, size_t ws_size,
                              hipStream_t stream) {
    const float* ht     = (const float*)d_in[0];   // (N,B,H) f32
    const int*   rmat   = (const int*)  d_in[1];   // (B,N,N) i32
    const float* dmat   = (const float*)d_in[2];   // (B,N,N) f32
    const float* mask   = (const float*)d_in[3];   // (B,N)   f32
    const int*   cog    = (const int*)  d_in[4];   // (B,N,N) i32
    const float* domain = (const float*)d_in[5];   // (72,72) f32
    float* out = (float*)d_out;

    unsigned int* gmax = (unsigned int*)d_ws;
    __bf16* T = (__bf16*)((char*)d_ws + 256);      // 8 MiB bf16 transpose buffer

    hipMemsetAsync(d_ws, 0, 256, stream);          // gmax = 0.0f
    k_transpose<<<dim3(16, 64), 256, 0, stream>>>(ht, T);
    k_main<<<dim3(256), 512, 0, stream>>>(cog, rmat, dmat, mask, domain, T, out, gmax);
    k_scale<<<4096, 256, 0, stream>>>(out, mask, gmax);
}

// Round 8
// 238.335 us; speedup vs baseline: 1.1649x; 1.1649x over previous
//
#include <hip/hip_runtime.h>

// hardwiredAttention: out[b,i,h] = sum_j w[b,i,j] * h_t[j,b,h]
//   w = m_i*m_j*relu(domain[cog,r]-d) / max(w)
// R8 = R7 pipeline (VGPR global loads -> ds_write staging, loads in flight
// across lgkm-only asm barriers) with ARRAY-FREE staging: R7's ldw[][]/gw[]/
// wo[] arrays landed in scratch (+235 MB HBM round-trip, WRITE 16->212 MB).
// Now: 3 base pointers (array index q>>1 is compile-time), one scalar LDS
// offset, individually named int4 staging registers. T-tile padded [128][40]
// to break 8-way ds_read_b128 conflicts.

#define B_   64
#define N_   512
#define H_   128
#define NCOG 72
#define NRB  72

typedef __bf16 bf16x8 __attribute__((ext_vector_type(8)));
typedef float  f32x4  __attribute__((ext_vector_type(4)));

// ---------- h_t[j][b][h] fp32 -> T[b][h][j] bf16 ----------
__global__ __launch_bounds__(256) void k_transpose(const float* __restrict__ ht,
                                                   __bf16* __restrict__ T) {
    __shared__ __bf16 tile[32][136];
    const int jt = blockIdx.x * 32;
    const int b  = blockIdx.y;
    const int t  = threadIdx.x;
    {
        const int jj = t >> 3;
        const int h0 = (t & 7) << 4;
        const float* src = ht + ((size_t)(jt + jj) * B_ + b) * H_ + h0;
        float4 v0 = *(const float4*)(src + 0);
        float4 v1 = *(const float4*)(src + 4);
        float4 v2 = *(const float4*)(src + 8);
        float4 v3 = *(const float4*)(src + 12);
        __bf16* dst = &tile[jj][h0];
        dst[0]=(__bf16)v0.x; dst[1]=(__bf16)v0.y; dst[2]=(__bf16)v0.z; dst[3]=(__bf16)v0.w;
        dst[4]=(__bf16)v1.x; dst[5]=(__bf16)v1.y; dst[6]=(__bf16)v1.z; dst[7]=(__bf16)v1.w;
        dst[8]=(__bf16)v2.x; dst[9]=(__bf16)v2.y; dst[10]=(__bf16)v2.z; dst[11]=(__bf16)v2.w;
        dst[12]=(__bf16)v3.x; dst[13]=(__bf16)v3.y; dst[14]=(__bf16)v3.z; dst[15]=(__bf16)v3.w;
    }
    __syncthreads();
    {
        const int h  = t >> 1;
        const int j0 = (t & 1) << 4;
        union { bf16x8 v[2]; __bf16 e[16]; } ob;
        #pragma unroll
        for (int q = 0; q < 16; ++q) ob.e[q] = tile[j0 + q][h];
        __bf16* dst = T + ((size_t)b * H_ + h) * N_ + jt + j0;
        *(bf16x8*)(dst + 0) = ob.v[0];
        *(bf16x8*)(dst + 8) = ob.v[1];
    }
}

// ---------- fused kernel: VGPR-staged pipeline, lgkm-only barriers ----------
__global__ __launch_bounds__(512, 2) void k_main(const int* __restrict__ cog,
                                                 const int* __restrict__ rmat,
                                                 const float* __restrict__ dmat,
                                                 const float* __restrict__ mask,
                                                 const float* __restrict__ domain,
                                                 const __bf16* __restrict__ T,
                                                 float* __restrict__ out,
                                                 unsigned int* __restrict__ gmax) {
    __shared__ int    wt[2][3][4096];   // 96 KB: [buf][arr][row*32 + xor-swz chunk]
    __shared__ __bf16 tt[2][H_][40];    // 20 KB: [buf][h][k], k-pad 40 (2-way max)
    __shared__ float  sdom[NCOG * NRB]; // 20736 B
    __shared__ float  smask[N_];        // 2048 B
    __shared__ float  swmax[8];

    const int id = blockIdx.x;                    // 256 blocks = 1 round, 1/CU
    const int b  = (id & 7) + 8 * (id >> 5);      // same-b blocks share an XCD
    const int i0 = ((id >> 3) & 3) * 128;

    const int t = threadIdx.x, wave = t >> 6, lane = t & 63;

    for (int k = t; k < NCOG * NRB; k += 512) sdom[k] = domain[k];
    for (int k = t; k < N_; k += 512) smask[k] = mask[b * N_ + k];

    const size_t robase = ((size_t)b * N_ + i0) * N_;

    // ---- staging descriptors (all scalar) ----
    // stream q in 0..5: array = q>>1 (cog/rmat/dmat), row = (q&1)*64 + wave*8 + l8
    const int l8 = lane >> 3, l7 = lane & 7;
    const int row0 = wave * 8 + l8;                       // rows 0..63 (q even)
    const size_t goff0 = robase + (size_t)row0 * N_ + l7 * 4;
    const int*   cp = cog  + goff0;
    const int*   rp = rmat + goff0;
    const int*   dp = (const int*)dmat + goff0;
    const int    o0 = row0 * 32 + ((l7 ^ l8) * 4);        // ints; +2048 per 64 rows
    const __bf16* tp = T + (size_t)b * H_ * N_
                         + (size_t)(wave * 16 + (lane >> 2)) * N_ + (lane & 3) * 8;
    const int    ot = (wave * 16 + (lane >> 2)) * 40 + (lane & 3) * 8;  // bf16 units

    int4 v0, v1, v2, v3, v4, v5, vt;   // parity-0 staging regs
    int4 u0, u1, u2, u3, u4, u5, ut;   // parity-1 staging regs

    #define ISSUE(n, A0,A1,A2,A3,A4,A5,AT) do {           \
        const int kk_ = (n) * 32;                          \
        A0 = *(const int4*)(cp + kk_);                     \
        A1 = *(const int4*)(cp + 64 * N_ + kk_);           \
        A2 = *(const int4*)(rp + kk_);                     \
        A3 = *(const int4*)(rp + 64 * N_ + kk_);           \
        A4 = *(const int4*)(dp + kk_);                     \
        A5 = *(const int4*)(dp + 64 * N_ + kk_);           \
        AT = *(const int4*)(tp + kk_); } while (0)

    #define STAGE(par, A0,A1,A2,A3,A4,A5,AT) do {          \
        int* wb = &wt[par][0][0];                          \
        *(int4*)(wb + o0)         = A0;                    \
        *(int4*)(wb + o0 + 2048)  = A1;                    \
        *(int4*)(wb + o0 + 4096)  = A2;                    \
        *(int4*)(wb + o0 + 6144)  = A3;                    \
        *(int4*)(wb + o0 + 8192)  = A4;                    \
        *(int4*)(wb + o0 + 10240) = A5;                    \
        *(int4*)(&tt[par][0][0] + ot) = AT; } while (0)

    // ---- consumer descriptors ----
    const int quad = lane >> 4, lrow = lane & 15;
    const int row  = wave * 16 + lrow;            // local 0..127
    const int g0   = row * 32 + (((quad * 2) ^ (lrow & 7)) * 4);
    const int g1   = g0 ^ 4;

    f32x4 acc[8];
    #pragma unroll
    for (int i = 0; i < 8; ++i) acc[i] = (f32x4)0.0f;
    float wmax = 0.0f;

    #define COMPUTE(s, par) do {                                                \
        const int jb = (s) * 32 + quad * 8;                                     \
        const int* wp = &wt[par][0][0];                                         \
        union { int4 v[2]; int   e[8]; } ci, ri;                                \
        union { int4 v[2]; float e[8]; } di;                                    \
        ci.v[0] = *(const int4*)(wp + g0);        ci.v[1] = *(const int4*)(wp + g1);        \
        ri.v[0] = *(const int4*)(wp + 4096 + g0); ri.v[1] = *(const int4*)(wp + 4096 + g1); \
        di.v[0] = *(const int4*)(wp + 8192 + g0); di.v[1] = *(const int4*)(wp + 8192 + g1); \
        bf16x8 bf0 = *(const bf16x8*)&tt[par][0 * 16 + lrow][quad * 8];         \
        bf16x8 bf1 = *(const bf16x8*)&tt[par][1 * 16 + lrow][quad * 8];         \
        bf16x8 bf2 = *(const bf16x8*)&tt[par][2 * 16 + lrow][quad * 8];         \
        bf16x8 bf3 = *(const bf16x8*)&tt[par][3 * 16 + lrow][quad * 8];         \
        bf16x8 bf4 = *(const bf16x8*)&tt[par][4 * 16 + lrow][quad * 8];         \
        bf16x8 bf5 = *(const bf16x8*)&tt[par][5 * 16 + lrow][quad * 8];         \
        bf16x8 bf6 = *(const bf16x8*)&tt[par][6 * 16 + lrow][quad * 8];         \
        bf16x8 bf7 = *(const bf16x8*)&tt[par][7 * 16 + lrow][quad * 8];         \
        union { bf16x8 v8; __bf16 e[8]; } af;                                   \
        _Pragma("unroll")                                                       \
        for (int q = 0; q < 8; ++q) {                                           \
            float val = sdom[ci.e[q] * NRB + ri.e[q]] - di.e[q];                \
            val = fmaxf(val, 0.0f) * smask[jb + q];                             \
            wmax = fmaxf(wmax, val);                                            \
            af.e[q] = (__bf16)val;                                              \
        }                                                                       \
        acc[0] = __builtin_amdgcn_mfma_f32_16x16x32_bf16(af.v8, bf0, acc[0], 0, 0, 0); \
        acc[1] = __builtin_amdgcn_mfma_f32_16x16x32_bf16(af.v8, bf1, acc[1], 0, 0, 0); \
        acc[2] = __builtin_amdgcn_mfma_f32_16x16x32_bf16(af.v8, bf2, acc[2], 0, 0, 0); \
        acc[3] = __builtin_amdgcn_mfma_f32_16x16x32_bf16(af.v8, bf3, acc[3], 0, 0, 0); \
        acc[4] = __builtin_amdgcn_mfma_f32_16x16x32_bf16(af.v8, bf4, acc[4], 0, 0, 0); \
        acc[5] = __builtin_amdgcn_mfma_f32_16x16x32_bf16(af.v8, bf5, acc[5], 0, 0, 0); \
        acc[6] = __builtin_amdgcn_mfma_f32_16x16x32_bf16(af.v8, bf6, acc[6], 0, 0, 0); \
        acc[7] = __builtin_amdgcn_mfma_f32_16x16x32_bf16(af.v8, bf7, acc[7], 0, 0, 0); \
    } while (0)

    // lgkm-only barrier: LDS writes published, global loads stay in flight
    #define LBAR asm volatile("s_waitcnt lgkmcnt(0)\n\ts_barrier" ::: "memory")

    // prologue: batches 0,1 in flight; stage batch 0 (compiler waits vmcnt(7))
    ISSUE(0, v0, v1, v2, v3, v4, v5, vt);
    ISSUE(1, u0, u1, u2, u3, u4, u5, ut);
    STAGE(0, v0, v1, v2, v3, v4, v5, vt);
    LBAR;

    for (int sp = 0; sp < 8; ++sp) {
        const int s0 = sp * 2, s1 = s0 + 1;
        if (s0 < 14) ISSUE(s0 + 2, v0, v1, v2, v3, v4, v5, vt);
        STAGE(1, u0, u1, u2, u3, u4, u5, ut);     // batch s0+1, loaded 1 step ago
        COMPUTE(s0, 0);
        LBAR;
        if (s1 < 14) ISSUE(s1 + 2, u0, u1, u2, u3, u4, u5, ut);
        if (s1 < 15) STAGE(0, v0, v1, v2, v3, v4, v5, vt);
        COMPUTE(s1, 1);
        LBAR;
    }
    #undef ISSUE
    #undef STAGE
    #undef COMPUTE
    #undef LBAR

    wmax *= smask[i0 + row];   // fold mask_i (all of this lane's w are row `row`)

    // block max -> one atomic
    #pragma unroll
    for (int off = 32; off > 0; off >>= 1)
        wmax = fmaxf(wmax, __shfl_down(wmax, off));
    if (lane == 0) swmax[wave] = wmax;
    __syncthreads();
    if (t == 0) {
        float m = swmax[0];
        #pragma unroll
        for (int w = 1; w < 8; ++w) m = fmaxf(m, swmax[w]);
        atomicMax(gmax, __float_as_uint(m));   // floats >= 0: uint cmp == float cmp
    }

    // unnormalized output; D layout: col=lane&15, row=quad*4+reg
    const int orow0 = i0 + wave * 16 + quad * 4;
    #pragma unroll
    for (int nt = 0; nt < 8; ++nt) {
        #pragma unroll
        for (int r = 0; r < 4; ++r)
            out[((size_t)b * N_ + orow0 + r) * H_ + nt * 16 + lrow] = acc[nt][r];
    }
}

// ---------- scale by m_i / gmax ----------
__global__ __launch_bounds__(256) void k_scale(float* __restrict__ out,
                                               const float* __restrict__ mask,
                                               const unsigned int* __restrict__ gmax) {
    const float inv = 1.0f / __uint_as_float(*gmax);
    const int idx = blockIdx.x * 256 + threadIdx.x;     // 1,048,576 float4s
    const float m = mask[idx >> 5] * inv;               // 32 float4 per (b,i) row
    float4* p = (float4*)out;
    float4 v = p[idx];
    v.x *= m; v.y *= m; v.z *= m; v.w *= m;
    p[idx] = v;
}

extern "C" void kernel_launch(void* const* d_in, const int* in_sizes, int n_in,
                              void* d_out, int out_size, void* d_ws, size_t ws_size,
                              hipStream_t stream) {
    const float* ht     = (const float*)d_in[0];   // (N,B,H) f32
    const int*   rmat   = (const int*)  d_in[1];   // (B,N,N) i32
    const float* dmat   = (const float*)d_in[2];   // (B,N,N) f32
    const float* mask   = (const float*)d_in[3];   // (B,N)   f32
    const int*   cog    = (const int*)  d_in[4];   // (B,N,N) i32
    const float* domain = (const float*)d_in[5];   // (72,72) f32
    float* out = (float*)d_out;

    unsigned int* gmax = (unsigned int*)d_ws;
    __bf16* T = (__bf16*)((char*)d_ws + 256);      // 8 MiB bf16 transpose buffer

    hipMemsetAsync(d_ws, 0, 256, stream);          // gmax = 0.0f
    k_transpose<<<dim3(16, 64), 256, 0, stream>>>(ht, T);
    k_main<<<dim3(256), 512, 0, stream>>>(cog, rmat, dmat, mask, domain, T, out, gmax);
    k_scale<<<4096, 256, 0, stream>>>(out, mask, gmax);
}